// Round 6
// baseline (292.488 us; speedup 1.0000x reference)
//
#include <hip/hip_runtime.h>

#define H 1024
#define E 8
#define BLK 256
#define CAP 5120       // int(1.25 * 4096 * 8 / 8)
#define FBLK 1024

typedef float f32x4 __attribute__((ext_vector_type(4)));

// ---------------------------------------------------------------------------
// Kernel 1: fused router = streaming GEMV (hs . rw^T) + softmax + top-2
// renorm + dispatch/probs stores + per-block partial sums.
// Wave layout: lane = (t<<4)|f ; t = token-slot (4), f = H-slice (16 x f32x4).
// 2 tokens/lane, 8/wave, 32/block, grid = N/32 = 1024 blocks (4 blocks/CU).
// Depth-4 software pipeline: 8 loads in flight per lane. PLAIN loads/stores:
// d_in is restored (L3-dirty-resident) before every replay — nontemporal
// hints forced dirty-flush + HBM refetch (R5: FETCH 188MB, WRITE 269MB).
// w in 32 KB LDS; reads are 16-address broadcast patterns (conflict-free).
// ---------------------------------------------------------------------------
__global__ __launch_bounds__(BLK, 4) void router_kernel(
    const float* __restrict__ hs,
    const float* __restrict__ rw,
    float* __restrict__ dispatch,
    float* __restrict__ probs_out,
    float* __restrict__ partial)   // [16][nb] slot-major
{
    __shared__ float w_lds[E * H];   // 32 KB

    const int tid  = threadIdx.x;
    const int wave = tid >> 6;
    const int lane = tid & 63;
    const int t    = lane >> 4;
    const int f    = lane & 15;
    const int wid  = blockIdx.x * (BLK / 64) + wave;
    const size_t tok0 = (size_t)wid * 8 + t * 2;
    const float* h0 = hs + tok0 * H + 4 * f;

    // depth-4 prefetch issued BEFORE w staging so they overlap it
    f32x4 A0[4], A1[4];
#pragma unroll
    for (int j = 0; j < 4; ++j) {
        A0[j] = *(const f32x4*)(h0 + j * 64);
        A1[j] = *(const f32x4*)(h0 + H + j * 64);
    }

    for (int i = tid; i < E * H / 4; i += BLK)
        ((f32x4*)w_lds)[i] = ((const f32x4*)rw)[i];
    __syncthreads();

    float acc0[E], acc1[E];
#pragma unroll
    for (int e = 0; e < E; ++e) { acc0[e] = 0.f; acc1[e] = 0.f; }

#pragma unroll 4
    for (int c = 0; c < 16; ++c) {
        const int cur = c & 3;
        const f32x4 a0 = A0[cur], a1 = A1[cur];
        if (c < 12) {
            A0[cur] = *(const f32x4*)(h0 + (c + 4) * 64);
            A1[cur] = *(const f32x4*)(h0 + H + (c + 4) * 64);
        }
        const float* wb = w_lds + c * 64 + 4 * f;
#pragma unroll
        for (int eg = 0; eg < 2; ++eg) {
            f32x4 wv[4];
#pragma unroll
            for (int q = 0; q < 4; ++q)
                wv[q] = *(const f32x4*)(wb + (eg * 4 + q) * H);
#pragma unroll
            for (int q = 0; q < 4; ++q) {
                const int e = eg * 4 + q;
                acc0[e] = fmaf(a0[0], wv[q][0], acc0[e]);
                acc0[e] = fmaf(a0[1], wv[q][1], acc0[e]);
                acc0[e] = fmaf(a0[2], wv[q][2], acc0[e]);
                acc0[e] = fmaf(a0[3], wv[q][3], acc0[e]);
                acc1[e] = fmaf(a1[0], wv[q][0], acc1[e]);
                acc1[e] = fmaf(a1[1], wv[q][1], acc1[e]);
                acc1[e] = fmaf(a1[2], wv[q][2], acc1[e]);
                acc1[e] = fmaf(a1[3], wv[q][3], acc1[e]);
            }
        }
    }

    // Butterfly over the 16 f-lanes: every lane gets the full dots
#pragma unroll
    for (int e = 0; e < E; ++e) {
        float v0 = acc0[e], v1 = acc1[e];
        v0 += __shfl_xor(v0, 1); v1 += __shfl_xor(v1, 1);
        v0 += __shfl_xor(v0, 2); v1 += __shfl_xor(v1, 2);
        v0 += __shfl_xor(v0, 4); v1 += __shfl_xor(v1, 4);
        v0 += __shfl_xor(v0, 8); v1 += __shfl_xor(v1, 8);
        acc0[e] = v0; acc1[e] = v1;
    }

    // Per-lane slot for block reduction: slot = f (0..7 dispatch, 8..15 probs)
    const int se = f & 7;
    const int sk = f >> 3;
    float slotv = 0.f;

#pragma unroll
    for (int j = 0; j < 2; ++j) {
        const float* L = j ? acc1 : acc0;
        float mx = L[0];
#pragma unroll
        for (int e = 1; e < E; ++e) mx = fmaxf(mx, L[e]);
        float p[E], s = 0.f;
#pragma unroll
        for (int e = 0; e < E; ++e) { p[e] = expf(L[e] - mx); s += p[e]; }
        const float inv = 1.f / s;
#pragma unroll
        for (int e = 0; e < E; ++e) p[e] *= inv;

        // top-2, strict >, lowest index on ties (lax.top_k semantics)
        int i1 = 0;
#pragma unroll
        for (int e = 1; e < E; ++e) if (p[e] > p[i1]) i1 = e;
        int i2 = -1;
#pragma unroll
        for (int e = 0; e < E; ++e) {
            if (e == i1) continue;
            if (i2 < 0 || p[e] > p[i2]) i2 = e;
        }
        const float s12 = p[i1] + p[i2];
        const float w1 = p[i1] / s12;
        const float w2 = p[i2] / s12;

        const size_t tok = tok0 + j;
        if (f < 8) {
            const float de = (f == i1) ? w1 : ((f == i2) ? w2 : 0.f);
            dispatch[tok * E + f] = de;
        } else {
            probs_out[tok * E + (f - 8)] = p[f - 8];
        }
        slotv += sk ? p[se] : ((se == i1) ? w1 : ((se == i2) ? w2 : 0.f));
    }

    // Block reduction of the 16 slots (reuse w_lds; all waves past the loop)
    __syncthreads();
    float* red = w_lds;                  // 256 floats
    red[wave * 64 + lane] = slotv;       // = red[(wave*4+t)*16 + f]
    __syncthreads();
    if (tid < 16) {
        float s = 0.f;
#pragma unroll
        for (int k = 0; k < 16; ++k) s += red[k * 16 + tid];
        partial[(size_t)tid * gridDim.x + blockIdx.x] = s;   // slot-major
    }
}

// ---------------------------------------------------------------------------
// Kernel 2: reduce partials -> lb_loss; per-expert capacity enforcement
// (exact radix select, index-ordered ties). Early-exits when under capacity
// (always, in expectation: E[mass/expert]=4096 < 5120 — insurance path).
// ---------------------------------------------------------------------------
__global__ __launch_bounds__(FBLK) void finalize_kernel(
    float* __restrict__ dispatch,
    const float* __restrict__ partial,
    int nb,
    float* __restrict__ lb_out,
    int N)
{
    const int e    = blockIdx.x;
    const int tid  = threadIdx.x;
    const int lane = tid & 63;
    const int wv   = tid >> 6;           // 16 waves -> 16 slots

    __shared__ float g[16];
    {
        float v = 0.f;
        for (int b = lane; b < nb; b += 64) v += partial[(size_t)wv * nb + b];
#pragma unroll
        for (int off = 32; off; off >>= 1) v += __shfl_xor(v, off);
        if (lane == 0) g[wv] = v;
    }
    __syncthreads();

    if (e == 0 && tid == 0) {
        float s = 0.f;
        for (int i = 0; i < E; ++i) s += g[i] * g[E + i];
        *lb_out = 0.01f * s / (float)N;
    }

    const float tpe = g[e];
    if (!(tpe > (float)CAP)) return;     // block-uniform

    __shared__ unsigned hist[256];
    __shared__ unsigned sh_prefix;
    __shared__ int sh_k;

    unsigned prefix = 0;
    int k = CAP;

    for (int round = 0; round < 4; ++round) {
        const int shift = 24 - 8 * round;
        for (int i = tid; i < 256; i += FBLK) hist[i] = 0;
        __syncthreads();
        const unsigned mhi = (round == 0) ? 0u : (0xFFFFFFFFu << (shift + 8));
        for (int i = tid; i < N; i += FBLK) {
            const unsigned bits = __float_as_uint(dispatch[(size_t)i * E + e]);
            if ((bits & mhi) == (prefix & mhi))
                atomicAdd(&hist[(bits >> shift) & 255u], 1u);
        }
        __syncthreads();
        if (tid == 0) {
            int cum = 0;
            int d = 255;
            for (; d > 0; --d) {
                const int h = (int)hist[d];
                if (cum + h >= k) break;
                cum += h;
            }
            sh_prefix = prefix | ((unsigned)d << shift);
            sh_k = k - cum;
        }
        __syncthreads();
        prefix = sh_prefix;
        k = sh_k;
        __syncthreads();
    }

    const unsigned T = prefix;
    const unsigned r = (unsigned)k;

    __shared__ unsigned wave_cnt[FBLK / 64];
    __shared__ unsigned running;
    if (tid == 0) running = 0;
    __syncthreads();

    for (int base = 0; base < N; base += FBLK) {
        const int i = base + tid;
        const unsigned bits = __float_as_uint(dispatch[(size_t)i * E + e]);
        const bool eq = (bits == T);
        const unsigned long long bal = __ballot(eq);
        if (lane == 0) wave_cnt[wv] = (unsigned)__popcll(bal);
        __syncthreads();
        unsigned before = running;
        for (int w = 0; w < wv; ++w) before += wave_cnt[w];
        const unsigned rank = before + (unsigned)__popcll(bal & ((1ull << lane) - 1ull));
        const bool keep = (bits > T) || (eq && rank < r);
        if (!keep) dispatch[(size_t)i * E + e] = 0.f;
        __syncthreads();
        if (tid == 0) {
            unsigned tot = 0;
            for (int w = 0; w < FBLK / 64; ++w) tot += wave_cnt[w];
            running += tot;
        }
        __syncthreads();
    }
}

// ---------------------------------------------------------------------------
extern "C" void kernel_launch(void* const* d_in, const int* in_sizes, int n_in,
                              void* d_out, int out_size, void* d_ws, size_t ws_size,
                              hipStream_t stream)
{
    const float* hs = (const float*)d_in[0];
    const float* rw = (const float*)d_in[1];
    const int n_tokens = in_sizes[0] / H;          // 32768

    float* dispatch = (float*)d_out;               // [N*E]
    float* lb       = dispatch + (size_t)n_tokens * E;
    float* probs    = lb + 1;                      // [N*E]
    float* partial  = (float*)d_ws;                // [16][nb] fp32, fully written

    const int nb = n_tokens / 32;                  // 1024 blocks
    router_kernel<<<nb, BLK, 0, stream>>>(hs, rw, dispatch, probs, partial);
    finalize_kernel<<<E, FBLK, 0, stream>>>(dispatch, partial, nb, lb, n_tokens);
}

// Round 7
// 204.933 us; speedup vs baseline: 1.4272x; 1.4272x over previous
//
#include <hip/hip_runtime.h>

#define H 1024
#define E 8
#define BLK 256
#define CAP 5120       // int(1.25 * 4096 * 8 / 8)
#define FBLK 1024

typedef float f32x4 __attribute__((ext_vector_type(4)));

// ---------------------------------------------------------------------------
// Kernel 1: fused router = streaming GEMV (hs . rw^T) + softmax + top-2
// renorm + dispatch/probs stores + per-block partial sums.
// Wave layout: lane = (t<<4)|f ; t = token-slot (4), f = H-slice (16 x f32x4).
// 2 tokens/lane, 8/wave, 32/block, grid = N/32 = 1024 blocks.
// Depth-4 pipeline with FULLY-UNROLLED c-loop: R5/R6 used `A0[c&3]` under a
// partial unroll-4 — the unresolved dynamic index demoted A0/A1 to scratch
// (VGPR_Count=64, 270 MB of HBM spill writeback, router 157 us). Full unroll
// makes every index a constant -> arrays live in VGPRs.
// w in 32 KB LDS; reads are 16-address broadcast patterns (conflict-free).
// ---------------------------------------------------------------------------
__global__ __launch_bounds__(BLK, 4) void router_kernel(
    const float* __restrict__ hs,
    const float* __restrict__ rw,
    float* __restrict__ dispatch,
    float* __restrict__ probs_out,
    float* __restrict__ partial)   // [16][nb] slot-major
{
    __shared__ float w_lds[E * H];   // 32 KB

    const int tid  = threadIdx.x;
    const int wave = tid >> 6;
    const int lane = tid & 63;
    const int t    = lane >> 4;
    const int f    = lane & 15;
    const int wid  = blockIdx.x * (BLK / 64) + wave;
    const size_t tok0 = (size_t)wid * 8 + t * 2;
    const float* h0 = hs + tok0 * H + 4 * f;

    // depth-4 prefetch issued BEFORE w staging so they overlap it
    f32x4 A0[4], A1[4];
#pragma unroll
    for (int j = 0; j < 4; ++j) {
        A0[j] = *(const f32x4*)(h0 + j * 64);
        A1[j] = *(const f32x4*)(h0 + H + j * 64);
    }

    for (int i = tid; i < E * H / 4; i += BLK)
        ((f32x4*)w_lds)[i] = ((const f32x4*)rw)[i];
    __syncthreads();

    float acc0[E], acc1[E];
#pragma unroll
    for (int e = 0; e < E; ++e) { acc0[e] = 0.f; acc1[e] = 0.f; }

#pragma unroll   // FULL unroll: c is a constant in every body, A0[c&3] folds
    for (int c = 0; c < 16; ++c) {
        const f32x4 a0 = A0[c & 3], a1 = A1[c & 3];
        if (c < 12) {
            A0[c & 3] = *(const f32x4*)(h0 + (c + 4) * 64);
            A1[c & 3] = *(const f32x4*)(h0 + H + (c + 4) * 64);
        }
        const float* wb = w_lds + c * 64 + 4 * f;
#pragma unroll
        for (int eg = 0; eg < 2; ++eg) {
            f32x4 wv[4];
#pragma unroll
            for (int q = 0; q < 4; ++q)
                wv[q] = *(const f32x4*)(wb + (eg * 4 + q) * H);
#pragma unroll
            for (int q = 0; q < 4; ++q) {
                const int e = eg * 4 + q;
                acc0[e] = fmaf(a0[0], wv[q][0], acc0[e]);
                acc0[e] = fmaf(a0[1], wv[q][1], acc0[e]);
                acc0[e] = fmaf(a0[2], wv[q][2], acc0[e]);
                acc0[e] = fmaf(a0[3], wv[q][3], acc0[e]);
                acc1[e] = fmaf(a1[0], wv[q][0], acc1[e]);
                acc1[e] = fmaf(a1[1], wv[q][1], acc1[e]);
                acc1[e] = fmaf(a1[2], wv[q][2], acc1[e]);
                acc1[e] = fmaf(a1[3], wv[q][3], acc1[e]);
            }
        }
    }

    // Butterfly over the 16 f-lanes: every lane gets the full dots
#pragma unroll
    for (int e = 0; e < E; ++e) {
        float v0 = acc0[e], v1 = acc1[e];
        v0 += __shfl_xor(v0, 1); v1 += __shfl_xor(v1, 1);
        v0 += __shfl_xor(v0, 2); v1 += __shfl_xor(v1, 2);
        v0 += __shfl_xor(v0, 4); v1 += __shfl_xor(v1, 4);
        v0 += __shfl_xor(v0, 8); v1 += __shfl_xor(v1, 8);
        acc0[e] = v0; acc1[e] = v1;
    }

    // Per-lane slot for block reduction: slot = f (0..7 dispatch, 8..15 probs)
    const int se = f & 7;
    const int sk = f >> 3;
    float slotv = 0.f;

#pragma unroll
    for (int j = 0; j < 2; ++j) {
        const float* L = j ? acc1 : acc0;
        float mx = L[0];
#pragma unroll
        for (int e = 1; e < E; ++e) mx = fmaxf(mx, L[e]);
        float p[E], s = 0.f;
#pragma unroll
        for (int e = 0; e < E; ++e) { p[e] = expf(L[e] - mx); s += p[e]; }
        const float inv = 1.f / s;
#pragma unroll
        for (int e = 0; e < E; ++e) p[e] *= inv;

        // top-2, strict >, lowest index on ties (lax.top_k semantics)
        int i1 = 0;
#pragma unroll
        for (int e = 1; e < E; ++e) if (p[e] > p[i1]) i1 = e;
        int i2 = -1;
#pragma unroll
        for (int e = 0; e < E; ++e) {
            if (e == i1) continue;
            if (i2 < 0 || p[e] > p[i2]) i2 = e;
        }
        const float s12 = p[i1] + p[i2];
        const float w1 = p[i1] / s12;
        const float w2 = p[i2] / s12;

        const size_t tok = tok0 + j;
        if (f < 8) {
            const float de = (f == i1) ? w1 : ((f == i2) ? w2 : 0.f);
            dispatch[tok * E + f] = de;
        } else {
            probs_out[tok * E + (f - 8)] = p[f - 8];
        }
        slotv += sk ? p[se] : ((se == i1) ? w1 : ((se == i2) ? w2 : 0.f));
    }

    // Block reduction of the 16 slots (reuse w_lds; all waves past the loop)
    __syncthreads();
    float* red = w_lds;                  // 256 floats
    red[wave * 64 + lane] = slotv;       // = red[(wave*4+t)*16 + f]
    __syncthreads();
    if (tid < 16) {
        float s = 0.f;
#pragma unroll
        for (int k = 0; k < 16; ++k) s += red[k * 16 + tid];
        partial[(size_t)tid * gridDim.x + blockIdx.x] = s;   // slot-major
    }
}

// ---------------------------------------------------------------------------
// Kernel 2: reduce partials -> lb_loss; per-expert capacity enforcement
// (exact radix select, index-ordered ties). Early-exits when under capacity
// (always, in expectation: E[mass/expert]=4096 < 5120 — insurance path).
// ---------------------------------------------------------------------------
__global__ __launch_bounds__(FBLK) void finalize_kernel(
    float* __restrict__ dispatch,
    const float* __restrict__ partial,
    int nb,
    float* __restrict__ lb_out,
    int N)
{
    const int e    = blockIdx.x;
    const int tid  = threadIdx.x;
    const int lane = tid & 63;
    const int wv   = tid >> 6;           // 16 waves -> 16 slots

    __shared__ float g[16];
    {
        float v = 0.f;
        for (int b = lane; b < nb; b += 64) v += partial[(size_t)wv * nb + b];
#pragma unroll
        for (int off = 32; off; off >>= 1) v += __shfl_xor(v, off);
        if (lane == 0) g[wv] = v;
    }
    __syncthreads();

    if (e == 0 && tid == 0) {
        float s = 0.f;
        for (int i = 0; i < E; ++i) s += g[i] * g[E + i];
        *lb_out = 0.01f * s / (float)N;
    }

    const float tpe = g[e];
    if (!(tpe > (float)CAP)) return;     // block-uniform

    __shared__ unsigned hist[256];
    __shared__ unsigned sh_prefix;
    __shared__ int sh_k;

    unsigned prefix = 0;
    int k = CAP;

    for (int round = 0; round < 4; ++round) {
        const int shift = 24 - 8 * round;
        for (int i = tid; i < 256; i += FBLK) hist[i] = 0;
        __syncthreads();
        const unsigned mhi = (round == 0) ? 0u : (0xFFFFFFFFu << (shift + 8));
        for (int i = tid; i < N; i += FBLK) {
            const unsigned bits = __float_as_uint(dispatch[(size_t)i * E + e]);
            if ((bits & mhi) == (prefix & mhi))
                atomicAdd(&hist[(bits >> shift) & 255u], 1u);
        }
        __syncthreads();
        if (tid == 0) {
            int cum = 0;
            int d = 255;
            for (; d > 0; --d) {
                const int h = (int)hist[d];
                if (cum + h >= k) break;
                cum += h;
            }
            sh_prefix = prefix | ((unsigned)d << shift);
            sh_k = k - cum;
        }
        __syncthreads();
        prefix = sh_prefix;
        k = sh_k;
        __syncthreads();
    }

    const unsigned T = prefix;
    const unsigned r = (unsigned)k;

    __shared__ unsigned wave_cnt[FBLK / 64];
    __shared__ unsigned running;
    if (tid == 0) running = 0;
    __syncthreads();

    for (int base = 0; base < N; base += FBLK) {
        const int i = base + tid;
        const unsigned bits = __float_as_uint(dispatch[(size_t)i * E + e]);
        const bool eq = (bits == T);
        const unsigned long long bal = __ballot(eq);
        if (lane == 0) wave_cnt[wv] = (unsigned)__popcll(bal);
        __syncthreads();
        unsigned before = running;
        for (int w = 0; w < wv; ++w) before += wave_cnt[w];
        const unsigned rank = before + (unsigned)__popcll(bal & ((1ull << lane) - 1ull));
        const bool keep = (bits > T) || (eq && rank < r);
        if (!keep) dispatch[(size_t)i * E + e] = 0.f;
        __syncthreads();
        if (tid == 0) {
            unsigned tot = 0;
            for (int w = 0; w < FBLK / 64; ++w) tot += wave_cnt[w];
            running += tot;
        }
        __syncthreads();
    }
}

// ---------------------------------------------------------------------------
extern "C" void kernel_launch(void* const* d_in, const int* in_sizes, int n_in,
                              void* d_out, int out_size, void* d_ws, size_t ws_size,
                              hipStream_t stream)
{
    const float* hs = (const float*)d_in[0];
    const float* rw = (const float*)d_in[1];
    const int n_tokens = in_sizes[0] / H;          // 32768

    float* dispatch = (float*)d_out;               // [N*E]
    float* lb       = dispatch + (size_t)n_tokens * E;
    float* probs    = lb + 1;                      // [N*E]
    float* partial  = (float*)d_ws;                // [16][nb] fp32, fully written

    const int nb = n_tokens / 32;                  // 1024 blocks
    router_kernel<<<nb, BLK, 0, stream>>>(hs, rw, dispatch, probs, partial);
    finalize_kernel<<<E, FBLK, 0, stream>>>(dispatch, partial, nb, lb, n_tokens);
}

// Round 8
// 204.806 us; speedup vs baseline: 1.4281x; 1.0006x over previous
//
#include <hip/hip_runtime.h>

#define H 1024
#define E 8
#define BLK 256
#define CAP 5120       // int(1.25 * 4096 * 8 / 8)
#define FBLK 1024

typedef float f32x4 __attribute__((ext_vector_type(4)));

// ---------------------------------------------------------------------------
// Kernel 1: fused router = streaming GEMV (hs . rw^T) + softmax + top-2
// renorm + dispatch/probs stores + per-block partial sums.
// Wave layout: lane = (t<<4)|f ; t = token-slot (4), f = H-slice (16 x f32x4).
// 2 tokens/lane, 8/wave, 32/block, grid = N/32 = 1024 blocks.
// __launch_bounds__(256,5): LDS 32KB/block -> exactly 5 blocks/CU (160 KB);
// VGPR capped ~96 so 20 waves/CU co-reside (+25% vs R7's 16). Pipeline depth
// cut 4->2 to keep live regs ~65 (depth-2 already gives 8x the Little's-law
// in-flight requirement). FULL unroll (R5/R6 lesson: partial unroll left a
// dynamic A0[c&3] index -> scratch spill, 270 MB HBM writeback).
// w in 32 KB LDS; reads are 16-address broadcast patterns (conflict-free).
// ---------------------------------------------------------------------------
__global__ __launch_bounds__(BLK, 5) void router_kernel(
    const float* __restrict__ hs,
    const float* __restrict__ rw,
    float* __restrict__ dispatch,
    float* __restrict__ probs_out,
    float* __restrict__ partial)   // [16][nb] slot-major
{
    __shared__ float w_lds[E * H];   // 32 KB

    const int tid  = threadIdx.x;
    const int wave = tid >> 6;
    const int lane = tid & 63;
    const int t    = lane >> 4;
    const int f    = lane & 15;
    const int wid  = blockIdx.x * (BLK / 64) + wave;
    const size_t tok0 = (size_t)wid * 8 + t * 2;
    const float* h0 = hs + tok0 * H + 4 * f;

    // depth-2 prefetch issued BEFORE w staging so they overlap it
    f32x4 A0[2], A1[2];
#pragma unroll
    for (int j = 0; j < 2; ++j) {
        A0[j] = *(const f32x4*)(h0 + j * 64);
        A1[j] = *(const f32x4*)(h0 + H + j * 64);
    }

    for (int i = tid; i < E * H / 4; i += BLK)
        ((f32x4*)w_lds)[i] = ((const f32x4*)rw)[i];
    __syncthreads();

    float acc0[E], acc1[E];
#pragma unroll
    for (int e = 0; e < E; ++e) { acc0[e] = 0.f; acc1[e] = 0.f; }

#pragma unroll   // FULL unroll: c is a constant in every body, A0[c&1] folds
    for (int c = 0; c < 16; ++c) {
        const f32x4 a0 = A0[c & 1], a1 = A1[c & 1];
        if (c < 14) {
            A0[c & 1] = *(const f32x4*)(h0 + (c + 2) * 64);
            A1[c & 1] = *(const f32x4*)(h0 + H + (c + 2) * 64);
        }
        const float* wb = w_lds + c * 64 + 4 * f;
#pragma unroll
        for (int eg = 0; eg < 2; ++eg) {
            f32x4 wv[4];
#pragma unroll
            for (int q = 0; q < 4; ++q)
                wv[q] = *(const f32x4*)(wb + (eg * 4 + q) * H);
#pragma unroll
            for (int q = 0; q < 4; ++q) {
                const int e = eg * 4 + q;
                acc0[e] = fmaf(a0[0], wv[q][0], acc0[e]);
                acc0[e] = fmaf(a0[1], wv[q][1], acc0[e]);
                acc0[e] = fmaf(a0[2], wv[q][2], acc0[e]);
                acc0[e] = fmaf(a0[3], wv[q][3], acc0[e]);
                acc1[e] = fmaf(a1[0], wv[q][0], acc1[e]);
                acc1[e] = fmaf(a1[1], wv[q][1], acc1[e]);
                acc1[e] = fmaf(a1[2], wv[q][2], acc1[e]);
                acc1[e] = fmaf(a1[3], wv[q][3], acc1[e]);
            }
        }
    }

    // Butterfly over the 16 f-lanes: every lane gets the full dots
#pragma unroll
    for (int e = 0; e < E; ++e) {
        float v0 = acc0[e], v1 = acc1[e];
        v0 += __shfl_xor(v0, 1); v1 += __shfl_xor(v1, 1);
        v0 += __shfl_xor(v0, 2); v1 += __shfl_xor(v1, 2);
        v0 += __shfl_xor(v0, 4); v1 += __shfl_xor(v1, 4);
        v0 += __shfl_xor(v0, 8); v1 += __shfl_xor(v1, 8);
        acc0[e] = v0; acc1[e] = v1;
    }

    // Per-lane slot for block reduction: slot = f (0..7 dispatch, 8..15 probs)
    const int se = f & 7;
    const int sk = f >> 3;
    float slotv = 0.f;

#pragma unroll
    for (int j = 0; j < 2; ++j) {
        const float* L = j ? acc1 : acc0;
        float mx = L[0];
#pragma unroll
        for (int e = 1; e < E; ++e) mx = fmaxf(mx, L[e]);
        float p[E], s = 0.f;
#pragma unroll
        for (int e = 0; e < E; ++e) { p[e] = expf(L[e] - mx); s += p[e]; }
        const float inv = 1.f / s;
#pragma unroll
        for (int e = 0; e < E; ++e) p[e] *= inv;

        // top-2, strict >, lowest index on ties (lax.top_k semantics)
        int i1 = 0;
#pragma unroll
        for (int e = 1; e < E; ++e) if (p[e] > p[i1]) i1 = e;
        int i2 = -1;
#pragma unroll
        for (int e = 0; e < E; ++e) {
            if (e == i1) continue;
            if (i2 < 0 || p[e] > p[i2]) i2 = e;
        }
        const float s12 = p[i1] + p[i2];
        const float w1 = p[i1] / s12;
        const float w2 = p[i2] / s12;

        const size_t tok = tok0 + j;
        if (f < 8) {
            const float de = (f == i1) ? w1 : ((f == i2) ? w2 : 0.f);
            dispatch[tok * E + f] = de;
        } else {
            probs_out[tok * E + (f - 8)] = p[f - 8];
        }
        slotv += sk ? p[se] : ((se == i1) ? w1 : ((se == i2) ? w2 : 0.f));
    }

    // Block reduction of the 16 slots (reuse w_lds; all waves past the loop)
    __syncthreads();
    float* red = w_lds;                  // 256 floats
    red[wave * 64 + lane] = slotv;       // = red[(wave*4+t)*16 + f]
    __syncthreads();
    if (tid < 16) {
        float s = 0.f;
#pragma unroll
        for (int k = 0; k < 16; ++k) s += red[k * 16 + tid];
        partial[(size_t)tid * gridDim.x + blockIdx.x] = s;   // slot-major
    }
}

// ---------------------------------------------------------------------------
// Kernel 2: reduce partials -> lb_loss; per-expert capacity enforcement
// (exact radix select, index-ordered ties). Early-exits when under capacity
// (always, in expectation: E[mass/expert]=4096 < 5120 — insurance path).
// ---------------------------------------------------------------------------
__global__ __launch_bounds__(FBLK) void finalize_kernel(
    float* __restrict__ dispatch,
    const float* __restrict__ partial,
    int nb,
    float* __restrict__ lb_out,
    int N)
{
    const int e    = blockIdx.x;
    const int tid  = threadIdx.x;
    const int lane = tid & 63;
    const int wv   = tid >> 6;           // 16 waves -> 16 slots

    __shared__ float g[16];
    {
        float v = 0.f;
        for (int b = lane; b < nb; b += 64) v += partial[(size_t)wv * nb + b];
#pragma unroll
        for (int off = 32; off; off >>= 1) v += __shfl_xor(v, off);
        if (lane == 0) g[wv] = v;
    }
    __syncthreads();

    if (e == 0 && tid == 0) {
        float s = 0.f;
        for (int i = 0; i < E; ++i) s += g[i] * g[E + i];
        *lb_out = 0.01f * s / (float)N;
    }

    const float tpe = g[e];
    if (!(tpe > (float)CAP)) return;     // block-uniform

    __shared__ unsigned hist[256];
    __shared__ unsigned sh_prefix;
    __shared__ int sh_k;

    unsigned prefix = 0;
    int k = CAP;

    for (int round = 0; round < 4; ++round) {
        const int shift = 24 - 8 * round;
        for (int i = tid; i < 256; i += FBLK) hist[i] = 0;
        __syncthreads();
        const unsigned mhi = (round == 0) ? 0u : (0xFFFFFFFFu << (shift + 8));
        for (int i = tid; i < N; i += FBLK) {
            const unsigned bits = __float_as_uint(dispatch[(size_t)i * E + e]);
            if ((bits & mhi) == (prefix & mhi))
                atomicAdd(&hist[(bits >> shift) & 255u], 1u);
        }
        __syncthreads();
        if (tid == 0) {
            int cum = 0;
            int d = 255;
            for (; d > 0; --d) {
                const int h = (int)hist[d];
                if (cum + h >= k) break;
                cum += h;
            }
            sh_prefix = prefix | ((unsigned)d << shift);
            sh_k = k - cum;
        }
        __syncthreads();
        prefix = sh_prefix;
        k = sh_k;
        __syncthreads();
    }

    const unsigned T = prefix;
    const unsigned r = (unsigned)k;

    __shared__ unsigned wave_cnt[FBLK / 64];
    __shared__ unsigned running;
    if (tid == 0) running = 0;
    __syncthreads();

    for (int base = 0; base < N; base += FBLK) {
        const int i = base + tid;
        const unsigned bits = __float_as_uint(dispatch[(size_t)i * E + e]);
        const bool eq = (bits == T);
        const unsigned long long bal = __ballot(eq);
        if (lane == 0) wave_cnt[wv] = (unsigned)__popcll(bal);
        __syncthreads();
        unsigned before = running;
        for (int w = 0; w < wv; ++w) before += wave_cnt[w];
        const unsigned rank = before + (unsigned)__popcll(bal & ((1ull << lane) - 1ull));
        const bool keep = (bits > T) || (eq && rank < r);
        if (!keep) dispatch[(size_t)i * E + e] = 0.f;
        __syncthreads();
        if (tid == 0) {
            unsigned tot = 0;
            for (int w = 0; w < FBLK / 64; ++w) tot += wave_cnt[w];
            running += tot;
        }
        __syncthreads();
    }
}

// ---------------------------------------------------------------------------
extern "C" void kernel_launch(void* const* d_in, const int* in_sizes, int n_in,
                              void* d_out, int out_size, void* d_ws, size_t ws_size,
                              hipStream_t stream)
{
    const float* hs = (const float*)d_in[0];
    const float* rw = (const float*)d_in[1];
    const int n_tokens = in_sizes[0] / H;          // 32768

    float* dispatch = (float*)d_out;               // [N*E]
    float* lb       = dispatch + (size_t)n_tokens * E;
    float* probs    = lb + 1;                      // [N*E]
    float* partial  = (float*)d_ws;                // [16][nb] fp32, fully written

    const int nb = n_tokens / 32;                  // 1024 blocks
    router_kernel<<<nb, BLK, 0, stream>>>(hs, rw, dispatch, probs, partial);
    finalize_kernel<<<E, FBLK, 0, stream>>>(dispatch, partial, nb, lb, n_tokens);
}